// Round 7
// baseline (149.795 us; speedup 1.0000x reference)
//
#include <hip/hip_runtime.h>
#include <hip/hip_bf16.h>
#include <cstdint>

#define N_NODES 50000
#define N_EDGES 800000
#define D_IN 128
#define D_HID 256
#define D_OUT 128

typedef __bf16 bf16;
typedef __bf16 bf16x8 __attribute__((ext_vector_type(8)));
typedef __bf16 bf16x4 __attribute__((ext_vector_type(4)));
typedef float f32x4 __attribute__((ext_vector_type(4)));
typedef unsigned int u32x4 __attribute__((ext_vector_type(4)));

__device__ __forceinline__ float bflo(unsigned p) {
  return __uint_as_float(p << 16);
}
__device__ __forceinline__ float bfhi(unsigned p) {
  return __uint_as_float(p & 0xffff0000u);
}
__device__ __forceinline__ unsigned pack_bf2(float fx, float fy) {
  union { struct { bf16 x, y; } h; unsigned i; } u;
  u.h.x = (bf16)fx; u.h.y = (bf16)fy;
  return u.i;
}

// ---------------------------------------------------------------------------
// Kernel 1: prep + CSR fused (unchanged — ~8 us).
// ---------------------------------------------------------------------------
__global__ __launch_bounds__(256) void prep_csr_kernel(
    const float* __restrict__ x, const int* __restrict__ dst,
    const float* __restrict__ w1, const float* __restrict__ w2,
    bf16* __restrict__ xb, bf16* __restrict__ w1t, bf16* __restrict__ w2t,
    int* __restrict__ offs) {
  const int i = blockIdx.x * 256 + threadIdx.x;
  float4 v = ((const float4*)x)[i];
  ((bf16x4*)xb)[i] = bf16x4{(bf16)v.x, (bf16)v.y, (bf16)v.z, (bf16)v.w};
  if (i < D_IN * D_HID) {            // 32768
    int k = i >> 8, n = i & 255;     // w1[k][n]
    w1t[n * D_IN + k] = (bf16)w1[i];
  } else if (i < 2 * D_IN * D_HID) { // next 32768
    int j = i - D_IN * D_HID;
    int k = j >> 7, n = j & 127;     // w2[k][n]
    w2t[n * D_HID + k] = (bf16)w2[j];
  }
  if (i < N_EDGES) {
    const int b = dst[i];
    const int a = (i == 0) ? -1 : dst[i - 1];
    for (int n = a + 1; n <= b; ++n) offs[n] = i;
    if (i == N_EDGES - 1)
      for (int n = b + 1; n <= N_NODES; ++n) offs[n] = N_EDGES;
  }
}

// ---------------------------------------------------------------------------
// Kernel 2: aggregation, ONE node per wave, quarter-wave edge packing
// (16 lanes x 16B = one 256B xb row; one gather instr serves 4 edges),
// batch depth 32 EDGES (r6 was 16): 8 sv + 8 vv + 8 gathers = 24 VMEM in
// flight per round. Poisson(16) degree => 99.96% of nodes finish in ONE
// dependent round (r6's 16-deep paid a second serial round on the ~47% of
// nodes with deg>16 — that round is the residual latency cost this version
// removes). Clamp+mask slots contribute 0; no dst loads, no flush logic.
// Cross-quarter reduce: 2 shfl_xor levels; lanes 0-15 do one 16B NT store.
// Self-term (1+eps)*x folded after reduction -> single bf16 rounding.
// Zero LDS, ~75 VGPR (<=128: no occupancy step crossed). grid: 12500 x 256.
// ---------------------------------------------------------------------------
__global__ __launch_bounds__(256) void agg_kernel(
    const bf16* __restrict__ xb, const int* __restrict__ src,
    const float* __restrict__ val, const int* __restrict__ offs,
    const float* __restrict__ eps, bf16* __restrict__ aggb) {
  const int node = (blockIdx.x << 2) | (threadIdx.x >> 6);  // [0, 50000)
  const int lane = threadIdx.x & 63;
  const int q = lane >> 4;          // which edge of the 4-pack
  const int c8 = (lane & 15) << 3;  // first of this lane's 8 channels
  const float scale = 1.0f + eps[0];

  const int s = __builtin_amdgcn_readfirstlane(offs[node]);
  const int e = __builtin_amdgcn_readfirstlane(offs[node + 1]);

  // self-row (independent; issued early)
  const u32x4 xg = *(const u32x4*)&xb[(long)node * D_IN + c8];

  float a0 = 0.f, a1 = 0.f, a2 = 0.f, a3 = 0.f,
        a4 = 0.f, a5 = 0.f, a6 = 0.f, a7 = 0.f;

  for (int i = s; i < e; i += 32) {   // 32 edges per round, 8 per quarter
    int id[8]; int sv[8]; float vv[8];
    #pragma unroll
    for (int t = 0; t < 8; ++t) {
      int raw = i + 4 * t + q;
      id[t] = (raw < e) ? raw : (e - 1);   // clamped, in-bounds
    }
    #pragma unroll
    for (int t = 0; t < 8; ++t) sv[t] = src[id[t]];
    #pragma unroll
    for (int t = 0; t < 8; ++t) {
      float vl = val[id[t]];
      vv[t] = (i + 4 * t + q < e) ? vl : 0.f;  // masked slots contribute 0
    }
    u32x4 g[8];
    #pragma unroll
    for (int t = 0; t < 8; ++t)
      g[t] = *(const u32x4*)&xb[(long)sv[t] * D_IN + c8];
    #pragma unroll
    for (int t = 0; t < 8; ++t) {
      a0 = fmaf(vv[t], bflo(g[t][0]), a0);
      a1 = fmaf(vv[t], bfhi(g[t][0]), a1);
      a2 = fmaf(vv[t], bflo(g[t][1]), a2);
      a3 = fmaf(vv[t], bfhi(g[t][1]), a3);
      a4 = fmaf(vv[t], bflo(g[t][2]), a4);
      a5 = fmaf(vv[t], bfhi(g[t][2]), a5);
      a6 = fmaf(vv[t], bflo(g[t][3]), a6);
      a7 = fmaf(vv[t], bfhi(g[t][3]), a7);
    }
  }

  // reduce the 4 quarter-wave partials (same 8 channels, disjoint edges)
  a0 += __shfl_xor(a0, 16); a0 += __shfl_xor(a0, 32);
  a1 += __shfl_xor(a1, 16); a1 += __shfl_xor(a1, 32);
  a2 += __shfl_xor(a2, 16); a2 += __shfl_xor(a2, 32);
  a3 += __shfl_xor(a3, 16); a3 += __shfl_xor(a3, 32);
  a4 += __shfl_xor(a4, 16); a4 += __shfl_xor(a4, 32);
  a5 += __shfl_xor(a5, 16); a5 += __shfl_xor(a5, 32);
  a6 += __shfl_xor(a6, 16); a6 += __shfl_xor(a6, 32);
  a7 += __shfl_xor(a7, 16); a7 += __shfl_xor(a7, 32);

  if (lane < 16) {
    // fold self-term; single f32->bf16 rounding per output channel
    a0 = fmaf(scale, bflo(xg[0]), a0);
    a1 = fmaf(scale, bfhi(xg[0]), a1);
    a2 = fmaf(scale, bflo(xg[1]), a2);
    a3 = fmaf(scale, bfhi(xg[1]), a3);
    a4 = fmaf(scale, bflo(xg[2]), a4);
    a5 = fmaf(scale, bfhi(xg[2]), a5);
    a6 = fmaf(scale, bflo(xg[3]), a6);
    a7 = fmaf(scale, bfhi(xg[3]), a7);
    u32x4 o;
    o[0] = pack_bf2(a0, a1);
    o[1] = pack_bf2(a2, a3);
    o[2] = pack_bf2(a4, a5);
    o[3] = pack_bf2(a6, a7);
    __builtin_nontemporal_store(o, (u32x4*)&aggb[(long)node * D_IN + c8]);
  }
}

// ---------------------------------------------------------------------------
// Kernel 3: FUSED 2-layer MLP (unchanged — ~13 us). h lives in LDS.
// Fragment layouts (verified): A: a[j]=A[l15][quad*8+j];
//   B: b[j]=Wt[l15][quad*8+j]; C: row=quad*4+r, col=l15.
// LDS = 17.4KB (As) + 33.8KB (Hs) = 51.2KB -> 3 blocks/CU.
// ---------------------------------------------------------------------------
__global__ __launch_bounds__(256) void mlp_fused(
    const bf16* __restrict__ A, const bf16* __restrict__ W1t,
    const bf16* __restrict__ W2t, const float* __restrict__ b1,
    const float* __restrict__ b2, float* __restrict__ out) {
  constexpr int LDA = 136;  // 272B row stride: 2-way bank aliasing only
  constexpr int LDH = 264;  // 528B row stride: 2-way bank aliasing only
  __shared__ alignas(16) bf16 As[64][LDA];
  __shared__ alignas(16) bf16 Hs[64][LDH];

  const int tid = threadIdx.x;
  const int m0 = blockIdx.x * 64;
  const int wave = tid >> 6;
  const int lane = tid & 63;
  const int l15 = lane & 15;
  const int quad = lane >> 4;

  #pragma unroll
  for (int it = 0; it < 4; ++it) {
    int idx = tid + it * 256;          // 0..1023
    int r = idx >> 4;
    int c8 = (idx & 15) << 3;
    int row = m0 + r; if (row >= N_NODES) row = N_NODES - 1;
    *(bf16x8*)&As[r][c8] = *(const bf16x8*)&A[(long)row * D_IN + c8];
  }

  bf16x8 w1f[4][4];  // [nf][ks]
  #pragma unroll
  for (int nf = 0; nf < 4; ++nf) {
    int n = wave * 64 + nf * 16 + l15;
    #pragma unroll
    for (int ks = 0; ks < 4; ++ks)
      w1f[nf][ks] = *(const bf16x8*)&W1t[(long)n * D_IN + ks * 32 + quad * 8];
  }
  __syncthreads();

  // Phase 1: h[0:64, wave*64 : wave*64+64) = relu(As @ W1 + b1)
  f32x4 acc[4][4] = {};  // [mf][nf]
  #pragma unroll
  for (int ks = 0; ks < 4; ++ks) {
    int kq = ks * 32 + quad * 8;
    bf16x8 a[4];
    #pragma unroll
    for (int mf = 0; mf < 4; ++mf)
      a[mf] = *(const bf16x8*)&As[mf * 16 + l15][kq];
    #pragma unroll
    for (int mf = 0; mf < 4; ++mf)
      #pragma unroll
      for (int nf = 0; nf < 4; ++nf)
        acc[mf][nf] = __builtin_amdgcn_mfma_f32_16x16x32_bf16(
            a[mf], w1f[nf][ks], acc[mf][nf], 0, 0, 0);
  }

  #pragma unroll
  for (int nf = 0; nf < 4; ++nf) {
    int col = wave * 64 + nf * 16 + l15;
    float bv = b1[col];
    #pragma unroll
    for (int mf = 0; mf < 4; ++mf)
      #pragma unroll
      for (int r = 0; r < 4; ++r)
        Hs[mf * 16 + quad * 4 + r][col] = (bf16)fmaxf(acc[mf][nf][r] + bv, 0.f);
  }

  bf16x8 w2f[2][8];  // [nf2][ks2]
  #pragma unroll
  for (int nf2 = 0; nf2 < 2; ++nf2) {
    int n = wave * 32 + nf2 * 16 + l15;
    #pragma unroll
    for (int ks2 = 0; ks2 < 8; ++ks2)
      w2f[nf2][ks2] = *(const bf16x8*)&W2t[(long)n * D_HID + ks2 * 32 + quad * 8];
  }
  __syncthreads();

  // Phase 2: out[0:64, wave*32 : wave*32+32) = Hs @ W2 + b2
  f32x4 acc2[4][2] = {};  // [mf][nf2]
  #pragma unroll
  for (int ks2 = 0; ks2 < 8; ++ks2) {
    int kq = ks2 * 32 + quad * 8;
    bf16x8 ha[4];
    #pragma unroll
    for (int mf = 0; mf < 4; ++mf)
      ha[mf] = *(const bf16x8*)&Hs[mf * 16 + l15][kq];
    #pragma unroll
    for (int mf = 0; mf < 4; ++mf)
      #pragma unroll
      for (int nf2 = 0; nf2 < 2; ++nf2)
        acc2[mf][nf2] = __builtin_amdgcn_mfma_f32_16x16x32_bf16(
            ha[mf], w2f[nf2][ks2], acc2[mf][nf2], 0, 0, 0);
  }

  #pragma unroll
  for (int nf2 = 0; nf2 < 2; ++nf2) {
    int col = wave * 32 + nf2 * 16 + l15;
    float bv = b2[col];
    #pragma unroll
    for (int mf = 0; mf < 4; ++mf)
      #pragma unroll
      for (int r = 0; r < 4; ++r) {
        int row = m0 + mf * 16 + quad * 4 + r;
        if (row < N_NODES)
          __builtin_nontemporal_store(acc2[mf][nf2][r] + bv,
                                      &out[(long)row * D_OUT + col]);
      }
  }
}

// ---------------------------------------------------------------------------
extern "C" void kernel_launch(void* const* d_in, const int* in_sizes, int n_in,
                              void* d_out, int out_size, void* d_ws, size_t ws_size,
                              hipStream_t stream) {
  const float* x    = (const float*)d_in[0];
  const int*   esrc = (const int*)d_in[1];
  const int*   edst = (const int*)d_in[2];
  const float* evl  = (const float*)d_in[3];
  const float* eps  = (const float*)d_in[4];
  const float* w1   = (const float*)d_in[5];
  const float* b1   = (const float*)d_in[6];
  const float* w2   = (const float*)d_in[7];
  const float* b2   = (const float*)d_in[8];
  float* out = (float*)d_out;

  // workspace layout (16B aligned)
  bf16* aggb = (bf16*)d_ws;                          // 12.8 MB
  bf16* xb   = aggb + (size_t)N_NODES * D_IN;        // 12.8 MB
  bf16* w1t  = xb + (size_t)N_NODES * D_IN;          // 64 KB
  bf16* w2t  = w1t + D_IN * D_HID;                   // 64 KB
  int*  offs = (int*)(w2t + D_HID * D_OUT);          // 200 KB

  prep_csr_kernel<<<(N_NODES * D_IN / 4) / 256, 256, 0, stream>>>(
      x, edst, w1, w2, xb, w1t, w2t, offs);
  agg_kernel<<<N_NODES / 4, 256, 0, stream>>>(
      xb, esrc, evl, offs, eps, aggb);
  mlp_fused<<<(N_NODES + 63) / 64, 256, 0, stream>>>(
      aggb, w1t, w2t, b1, b2, out);
}